// Round 4
// baseline (337.069 us; speedup 1.0000x reference)
//
#include <hip/hip_runtime.h>
#include <hip/hip_cooperative_groups.h>

namespace cg = cooperative_groups;

// Segment-mean + ReLU pooling, R3: single cooperative dispatch.
// R0/R1/R2 all ~89-90us despite wildly different read patterns -> read
// pattern is not the lever. Hypothesis split: (A) ~7us/dispatch graph-node
// overhead means accum was already ~65us (roofline); (B) pure-read ceiling
// ~4.8 TB/s. This round: fuse zero+accum+finalize into ONE cooperative
// kernel (no atomics: per-block partials to d_ws, grid.sync, per-segment
// gather). Story A predicts ~73us; story B predicts neutral.
//
// Sub-segments per 196-row chunk <= 3: adjacent segment sizes are
// 195+jitter-delta, any two consecutive sizes sum >= 196, so at most two
// segment starts fall strictly inside one chunk. (4 slots allocated.)

#define D_FEAT 512
#define NCOL4 (D_FEAT / 4)  // 128 float4 columns
#define MAX_SUB 4

__global__ __launch_bounds__(512) void fused_pool_kernel(
    const float4* __restrict__ in,  // [num_nodes, NCOL4]
    const int* __restrict__ idx,    // [num_graphs]
    float* __restrict__ out,        // [num_graphs, D_FEAT]
    float* __restrict__ ws,         // [nblocks, MAX_SUB, D_FEAT] partials
    int num_nodes, int num_graphs, int rows_per_blk) {
  const int b = blockIdx.x;
  const int col = threadIdx.x & (NCOL4 - 1);  // 0..127
  const int grp = threadIdx.x >> 7;           // 0..3

  __shared__ float4 part[3][NCOL4];

  // ---- Phase A: balanced fixed chunks -> per-(block,subseg) partial rows ----
  const int r0 = b * rows_per_blk;
  if (r0 < num_nodes) {
    const int r1 = min(r0 + rows_per_blk, num_nodes);

    // largest s with idx[s] <= r0 (block-uniform; idx 4KB, L2-hot)
    int lo = 0, hi = num_graphs - 1;
    while (lo < hi) {
      int mid = (lo + hi + 1) >> 1;
      if (idx[mid] <= r0) lo = mid;
      else hi = mid - 1;
    }
    int s = lo;
    int row = r0;
    int k = 0;

    while (row < r1 && k < MAX_SUB) {
      const int seg_end = (s + 1 < num_graphs) ? idx[s + 1] : num_nodes;
      const int e = min(seg_end, r1);

      float4 acc = make_float4(0.f, 0.f, 0.f, 0.f);
      for (int r = row + grp; r < e; r += 4) {
        float4 v = in[(size_t)r * NCOL4 + col];
        acc.x += v.x; acc.y += v.y; acc.z += v.z; acc.w += v.w;
      }

      if (grp > 0) part[grp - 1][col] = acc;
      __syncthreads();
      if (grp == 0) {
#pragma unroll
        for (int g = 0; g < 3; ++g) {
          float4 p = part[g][col];
          acc.x += p.x; acc.y += p.y; acc.z += p.z; acc.w += p.w;
        }
        ((float4*)ws)[((size_t)b * MAX_SUB + k) * NCOL4 + col] = acc;
      }
      __syncthreads();  // part[] reused next sub-segment

      row = e;
      ++s;
      ++k;
    }
  }

  __threadfence();      // make ws stores device-visible (cross-XCD)
  cg::this_grid().sync();

  // ---- Phase B: block s gathers partials for segment s, finalize ----
  const int s = b;
  if (s < num_graphs) {
    const int t = threadIdx.x;  // one float column each
    const int start = idx[s];
    const int end = (s + 1 < num_graphs) ? idx[s + 1] : num_nodes;
    const int b0 = start / rows_per_blk;
    const int b1 = (end - 1) / rows_per_blk;

    float sum = 0.f;
    for (int bb = b0; bb <= b1; ++bb) {
      // first segment of block bb: largest s' with idx[s'] <= bb*rows_per_blk
      const int rr = bb * rows_per_blk;
      int lo = 0, hi = num_graphs - 1;
      while (lo < hi) {
        int mid = (lo + hi + 1) >> 1;
        if (idx[mid] <= rr) lo = mid;
        else hi = mid - 1;
      }
      const int local = s - lo;
      if (local >= 0 && local < MAX_SUB)
        sum += ws[((size_t)bb * MAX_SUB + local) * D_FEAT + t];
    }
    const float inv = 1.0f / (float)(end - start);
    out[(size_t)s * D_FEAT + t] = fmaxf(sum * inv, 0.f);
  }
}

extern "C" void kernel_launch(void* const* d_in, const int* in_sizes, int n_in,
                              void* d_out, int out_size, void* d_ws,
                              size_t ws_size, hipStream_t stream) {
  const float4* in = (const float4*)d_in[0];
  const int* idx = (const int*)d_in[1];
  float* out = (float*)d_out;
  float* ws = (float*)d_ws;

  int num_nodes = in_sizes[0] / D_FEAT;  // 200000
  int num_graphs = in_sizes[1];          // 1024

  int nblocks = num_graphs;  // 1024: 4 blocks/CU, co-resident
  int rows_per_blk = (num_nodes + nblocks - 1) / nblocks;  // 196

  void* args[] = {(void*)&in, (void*)&idx, (void*)&out, (void*)&ws,
                  (void*)&num_nodes, (void*)&num_graphs, (void*)&rows_per_blk};
  hipLaunchCooperativeKernel((const void*)fused_pool_kernel, dim3(nblocks),
                             dim3(512), args, 0, stream);
}

// Round 5
// 78.454 us; speedup vs baseline: 4.2964x; 4.2964x over previous
//
#include <hip/hip_runtime.h>

// Segment-mean + ReLU pooling, R4: non-temporal streaming reads + 2 dispatches.
//
// R3's counters showed FETCH_SIZE ~= 202 MB (half the 412 MB input): the L3
// retains a pseudo-random half of d_in across graph replays, so HBM sees a
// "swiss-cheese" miss stream (alternating absent cachelines) with ruined DRAM
// page locality -- explaining why R0/R1/R2 all capped at ~5 TB/s regardless of
// access pattern. Fix under test: nt-hinted loads (evict-first) so the input
// never sticks in L2/L3; misses become contiguous streams.
// Also: 2 dispatches only -- accum writes per-(block,subseg) partials to d_ws
// (no atomics, no zero kernel), gather kernel finalizes per segment.
//
// Sub-segments per 196-row chunk <= 3 (consecutive segment sizes sum >= 196,
// so at most 2 starts strictly inside a chunk). MAX_SUB=4 slots for margin.

#define D_FEAT 512
#define NCOL4 (D_FEAT / 4)  // 128 float4 columns
#define MAX_SUB 4

typedef float f4 __attribute__((ext_vector_type(4)));

__global__ __launch_bounds__(512) void seg_accum_ws(
    const f4* __restrict__ in,   // [num_nodes, NCOL4]
    const int* __restrict__ idx, // [num_graphs]
    float* __restrict__ ws,      // [nblocks, MAX_SUB, D_FEAT]
    int num_nodes, int num_graphs, int rpb) {
  const int b = blockIdx.x;
  const int r0 = b * rpb;
  if (r0 >= num_nodes) return;
  const int r1 = min(r0 + rpb, num_nodes);

  const int lane = threadIdx.x & 63;
  const int w = threadIdx.x >> 6;  // wave 0..7

  __shared__ f4 part[8][NCOL4];  // 16 KB

  // largest s with idx[s] <= r0 (block-uniform; idx 4KB, cache-hot)
  int lo = 0, hi = num_graphs - 1;
  while (lo < hi) {
    int mid = (lo + hi + 1) >> 1;
    if (idx[mid] <= r0) lo = mid;
    else hi = mid - 1;
  }
  int s = lo;
  int row = r0;
  int k = 0;

  while (row < r1 && k < MAX_SUB) {
    const int seg_end = (s + 1 < num_graphs) ? idx[s + 1] : num_nodes;
    const int e = min(seg_end, r1);
    const int n = e - row;

    // wave w streams contiguous rows [wsr, wer) flat; dual accumulators
    // track the lane->column parity (even 64-blocks -> col lane, odd -> +64).
    const int wsr = row + (n * w) / 8;
    const int wer = row + (n * (w + 1)) / 8;

    f4 accA = {0.f, 0.f, 0.f, 0.f};
    f4 accB = {0.f, 0.f, 0.f, 0.f};

    int j = wsr * NCOL4 + lane;
    const int jend = wer * NCOL4;
    for (; j + 192 < jend; j += 256) {  // 4 independent nt loads in flight
      f4 v0 = __builtin_nontemporal_load(&in[j]);
      f4 v1 = __builtin_nontemporal_load(&in[j + 64]);
      f4 v2 = __builtin_nontemporal_load(&in[j + 128]);
      f4 v3 = __builtin_nontemporal_load(&in[j + 192]);
      accA += v0;
      accB += v1;
      accA += v2;
      accB += v3;
    }
    for (; j < jend; j += 64) {
      f4 v = __builtin_nontemporal_load(&in[j]);
      if ((((j - lane) >> 6) & 1) == 0) accA += v;
      else accB += v;
    }

    part[w][lane] = accA;
    part[w][lane + 64] = accB;
    __syncthreads();

    if (threadIdx.x < NCOL4) {  // one float4 column per thread
      f4 a = part[0][threadIdx.x];
#pragma unroll
      for (int ww = 1; ww < 8; ++ww) a += part[ww][threadIdx.x];
      ((f4*)ws)[((size_t)b * MAX_SUB + k) * NCOL4 + threadIdx.x] = a;
    }
    __syncthreads();  // part[] reused next sub-segment

    row = e;
    ++s;
    ++k;
  }
}

__global__ __launch_bounds__(512) void seg_gather(
    const float* __restrict__ ws, const int* __restrict__ idx,
    float* __restrict__ out, int num_nodes, int num_graphs, int rpb) {
  const int s = blockIdx.x;  // one block per segment
  if (s >= num_graphs) return;
  const int t = threadIdx.x;  // one float column per thread
  const int start = idx[s];
  const int end = (s + 1 < num_graphs) ? idx[s + 1] : num_nodes;
  const int b0 = start / rpb;
  const int b1 = (end - 1) / rpb;

  float sum = 0.f;
  for (int bb = b0; bb <= b1; ++bb) {
    // first segment of block bb's chunk
    const int rr = bb * rpb;
    int lo = 0, hi = num_graphs - 1;
    while (lo < hi) {
      int mid = (lo + hi + 1) >> 1;
      if (idx[mid] <= rr) lo = mid;
      else hi = mid - 1;
    }
    const int local = s - lo;
    if (local >= 0 && local < MAX_SUB)
      sum += ws[((size_t)bb * MAX_SUB + local) * D_FEAT + t];
  }
  out[(size_t)s * D_FEAT + t] = fmaxf(sum / (float)(end - start), 0.f);
}

extern "C" void kernel_launch(void* const* d_in, const int* in_sizes, int n_in,
                              void* d_out, int out_size, void* d_ws,
                              size_t ws_size, hipStream_t stream) {
  const f4* in = (const f4*)d_in[0];
  const int* idx = (const int*)d_in[1];
  float* out = (float*)d_out;
  float* ws = (float*)d_ws;  // needs 1024*4*512*4B = 8 MB

  const int num_nodes = in_sizes[0] / D_FEAT;  // 200000
  const int num_graphs = in_sizes[1];          // 1024

  const int nblocks = 1024;  // 4 equal chunks per CU
  const int rpb = (num_nodes + nblocks - 1) / nblocks;  // 196

  seg_accum_ws<<<dim3(nblocks), dim3(512), 0, stream>>>(in, idx, ws, num_nodes,
                                                        num_graphs, rpb);
  seg_gather<<<dim3(num_graphs), dim3(512), 0, stream>>>(ws, idx, out,
                                                         num_nodes, num_graphs,
                                                         rpb);
}